// Round 10
// baseline (384.965 us; speedup 1.0000x reference)
//
#include <hip/hip_runtime.h>
#include <cmath>

typedef unsigned short ushort_t;
typedef __attribute__((ext_vector_type(8))) short short8;
typedef __attribute__((ext_vector_type(4))) float floatx4;

// Problem constants
#define NH    12
#define T     1024
#define ROWS  4096      // B*T
#define NE    768
#define KPA   832       // bf16 K-pad for 769/780 (multiple of 64)
#define KPB   3136      // bf16 K-pad for 3076 (multiple of 64)
#define NEXP  3200      // padded expand N (3075 -> 25*128)
#define HEXP  3075
#define NSPLIT 3        // attention split-S factor

// ---------------- helpers ----------------
__device__ __forceinline__ ushort_t f2bf(float f) {
  union { float f; unsigned u; } v; v.f = f;
  unsigned r = v.u + 0x7fffu + ((v.u >> 16) & 1u);
  return (ushort_t)(r >> 16);
}
__device__ __forceinline__ float bf2f(ushort_t b) {
  union { unsigned u; float f; } v; v.u = ((unsigned)b) << 16;
  return v.f;
}
__device__ __forceinline__ float blk_reduce_sum(float v, float* sm) {
  #pragma unroll
  for (int o = 32; o > 0; o >>= 1) v += __shfl_xor(v, o, 64);
  int lane = threadIdx.x & 63, w = threadIdx.x >> 6;
  __syncthreads();
  if (lane == 0) sm[w] = v;
  __syncthreads();
  return sm[0] + sm[1] + sm[2] + sm[3];
}
__device__ __forceinline__ float red16_sum(float v) {
  #pragma unroll
  for (int o = 1; o < 16; o <<= 1) v += __shfl_xor(v, o, 64);
  return v;
}

// ---------------- merged prep: 4 weight pad-converts + aout pad zero ---------
#define NB_A 7488    // 2304*832/256
#define NB_B 2496    // 768*832/256
#define NB_C 10400   // 3200*832/256
#define NB_D 9408    // 768*3136/256
#define NB_E 16      // ROWS/256
__device__ __forceinline__ void cvt_elem(ushort_t* __restrict__ dst,
                                         const float* __restrict__ src,
                                         int idx, int srcRows, int srcK, int dstK) {
  int r = idx / dstK, c = idx - r * dstK;
  dst[idx] = (r < srcRows && c < srcK) ? f2bf(src[(size_t)r * srcK + c]) : (ushort_t)0;
}
__global__ __launch_bounds__(256) void prep_kernel(
    ushort_t* __restrict__ qkv_wb, const float* __restrict__ qkvw,
    ushort_t* __restrict__ proj_wb, const float* __restrict__ projw,
    ushort_t* __restrict__ exp_wb, const float* __restrict__ expw,
    ushort_t* __restrict__ shr_wb, const float* __restrict__ shrw,
    ushort_t* __restrict__ aout_bf) {
  int blk = blockIdx.x;
  int tid = threadIdx.x;
  if (blk < NB_A) {
    cvt_elem(qkv_wb, qkvw, blk * 256 + tid, 2304, 769, KPA);
  } else if (blk < NB_A + NB_B) {
    cvt_elem(proj_wb, projw, (blk - NB_A) * 256 + tid, 768, 780, KPA);
  } else if (blk < NB_A + NB_B + NB_C) {
    cvt_elem(exp_wb, expw, (blk - NB_A - NB_B) * 256 + tid, HEXP, 769, KPA);
  } else if (blk < NB_A + NB_B + NB_C + NB_D) {
    cvt_elem(shr_wb, shrw, (blk - NB_A - NB_B - NB_C) * 256 + tid, 768, 3076, KPB);
  } else {
    int r = (blk - NB_A - NB_B - NB_C - NB_D) * 256 + tid;
    ushort_t* p = aout_bf + (size_t)r * KPA + 780;
    #pragma unroll
    for (int j = 0; j < KPA - 780; ++j) p[j] = 0;
  }
}

// ---------------- layernorm + hyperboloid project -> bf16 (stride KPA) -------
__global__ __launch_bounds__(256) void ln_project(
    const float* __restrict__ xin, const float* __restrict__ g,
    const float* __restrict__ bb, const float* __restrict__ curv,
    ushort_t* __restrict__ outp) {
  __shared__ float sm[4];
  const int row = blockIdx.x;
  const int tid = threadIdx.x;
  const float* xr = xin + (size_t)row * NE;
  float xv[3];
  float s = 0.f, ss = 0.f;
  #pragma unroll
  for (int i = 0; i < 3; ++i) {
    xv[i] = xr[tid + 256 * i];
    s += xv[i]; ss += xv[i] * xv[i];
  }
  s = blk_reduce_sum(s, sm);
  ss = blk_reduce_sum(ss, sm);
  float mean = s * (1.f / 768.f);
  float var = ss * (1.f / 768.f) - mean * mean;
  float rstd = rsqrtf(var + 1e-5f);
  float yv[3]; float ys = 0.f;
  #pragma unroll
  for (int i = 0; i < 3; ++i) {
    int c = tid + 256 * i;
    yv[i] = (xv[i] - mean) * rstd * g[c] + bb[c];
    ys += yv[i] * yv[i];
  }
  ys = blk_reduce_sum(ys, sm);
  float tc = sqrtf(expf(curv[0]) + ys);
  ushort_t* orow = outp + (size_t)row * KPA;
  #pragma unroll
  for (int i = 0; i < 3; ++i) orow[1 + tid + 256 * i] = f2bf(yv[i]);
  if (tid == 0) orow[0] = f2bf(tc);
  if (tid < KPA - 769) orow[769 + tid] = 0;
}

// ---------------- bf16 MFMA NT GEMM, BK=64, swizzled LDS, optional split-K ---
// LDS chunk swizzle: 16B chunk of global chunk-idx g for row r stored at
// position g ^ (r&7); fragment reads then hit all 8 bank groups (2-way free).
__global__ __launch_bounds__(256) void gemm_bf16(
    const ushort_t* __restrict__ A, int lda,
    const ushort_t* __restrict__ W, int ldw,
    void* __restrict__ Cout, int ldc,
    int nkTot, int cpt,
    const float* __restrict__ bias, int biasN,
    const float* __restrict__ res, int ldres,
    int outMode, float* __restrict__ Cp) {
  __shared__ ushort_t As[128 * 64];
  __shared__ ushort_t Bs[128 * 64];
  const int tid = threadIdx.x;
  const int w = tid >> 6, lane = tid & 63;
  const int rowBase = (int)blockIdx.y << 7;
  const int colBase = (int)blockIdx.x << 7;
  const int wm = (w & 1) * 64, wn = (w >> 1) * 64;
  const int lm = lane & 15, quad = lane >> 4;
  const int p0 = quad ^ (lm & 7);   // fragment-read chunk position, s=0

  floatx4 acc[4][4];
  #pragma unroll
  for (int i = 0; i < 4; ++i)
    #pragma unroll
    for (int j = 0; j < 4; ++j) {
      floatx4 z = {0.f, 0.f, 0.f, 0.f};
      acc[i][j] = z;
    }

  const int kt0 = (int)blockIdx.z * cpt;
  const int kt1 = min(nkTot, kt0 + cpt);
  for (int kt = kt0; kt < kt1; ++kt) {
    __syncthreads();
    #pragma unroll
    for (int j = 0; j < 4; ++j) {
      int ci = j * 256 + tid;            // 16B chunk index 0..1023
      int r = ci >> 3;                   // row 0..127
      int g = (ci & 7) ^ (r & 7);        // global chunk stored at this position
      const ushort_t* ga = A + (size_t)(rowBase + r) * lda + kt * 64 + g * 8;
      const ushort_t* gb = W + (size_t)(colBase + r) * ldw + kt * 64 + g * 8;
      __builtin_amdgcn_global_load_lds(
          (const __attribute__((address_space(1))) void*)ga,
          (__attribute__((address_space(3))) void*)&As[(j * 256 + w * 64) * 8],
          16, 0, 0);
      __builtin_amdgcn_global_load_lds(
          (const __attribute__((address_space(1))) void*)gb,
          (__attribute__((address_space(3))) void*)&Bs[(j * 256 + w * 64) * 8],
          16, 0, 0);
    }
    __syncthreads();

    #pragma unroll
    for (int s = 0; s < 2; ++s) {
      const int ps = s ? (p0 ^ 4) : p0;
      short8 af[4], bfr[4];
      #pragma unroll
      for (int i = 0; i < 4; ++i) {
        af[i]  = *(const short8*)&As[(wm + i * 16 + lm) * 64 + ps * 8];
        bfr[i] = *(const short8*)&Bs[(wn + i * 16 + lm) * 64 + ps * 8];
      }
      #pragma unroll
      for (int i = 0; i < 4; ++i)
        #pragma unroll
        for (int jn = 0; jn < 4; ++jn)
          acc[i][jn] = __builtin_amdgcn_mfma_f32_16x16x32_bf16(
              af[i], bfr[jn], acc[i][jn], 0, 0, 0);
    }
  }

  if (gridDim.z > 1) {
    float* dst = Cp + (size_t)blockIdx.z * ROWS * ldc;
    #pragma unroll
    for (int i = 0; i < 4; ++i)
      #pragma unroll
      for (int jn = 0; jn < 4; ++jn) {
        const int col = colBase + wn + jn * 16 + lm;
        #pragma unroll
        for (int rg = 0; rg < 4; ++rg) {
          const int row = rowBase + wm + i * 16 + quad * 4 + rg;
          dst[(size_t)row * ldc + col] = acc[i][jn][rg];
        }
      }
  } else if (outMode == 1) {
    ushort_t* C = (ushort_t*)Cout;
    #pragma unroll
    for (int i = 0; i < 4; ++i)
      #pragma unroll
      for (int jn = 0; jn < 4; ++jn) {
        const int col = colBase + wn + jn * 16 + lm;
        const float bv = bias ? ((col < biasN) ? bias[col] : 0.f) : 0.f;
        #pragma unroll
        for (int rg = 0; rg < 4; ++rg) {
          const int row = rowBase + wm + i * 16 + quad * 4 + rg;
          C[(size_t)row * ldc + col] = f2bf(acc[i][jn][rg] + bv);
        }
      }
  } else {
    float* C = (float*)Cout;
    #pragma unroll
    for (int i = 0; i < 4; ++i)
      #pragma unroll
      for (int jn = 0; jn < 4; ++jn) {
        const int col = colBase + wn + jn * 16 + lm;
        const float bv = bias ? ((col < biasN) ? bias[col] : 0.f) : 0.f;
        #pragma unroll
        for (int rg = 0; rg < 4; ++rg) {
          const int row = rowBase + wm + i * 16 + quad * 4 + rg;
          float o = acc[i][jn][rg] + bv;
          if (res) o += res[(size_t)row * ldres + col];
          C[(size_t)row * ldc + col] = o;
        }
      }
  }
}

// ---------------- rotary + per-head hyperboloid project (bf16 in) ------------
__global__ __launch_bounds__(256) void rope_project(
    const ushort_t* __restrict__ qkv, const float* __restrict__ ac,
    ushort_t* __restrict__ qb, ushort_t* __restrict__ kb, ushort_t* __restrict__ vtb,
    float* __restrict__ q0, float* __restrict__ k0, float* __restrict__ v0) {
  int gid = blockIdx.x * 4 + (threadIdx.x >> 6);
  int lane = threadIdx.x & 63;
  int h = gid % NH;
  int bt = gid / NH;
  int t = bt & (T - 1);
  int b = bt >> 10;
  size_t base = (size_t)bt * 2304 + h * 64;
  float qv = bf2f(qkv[base + lane]);
  float kv = bf2f(qkv[base + 768 + lane]);
  float vv = bf2f(qkv[base + 1536 + lane]);
  int f = lane & 31;
  float ang = (float)t * powf(10000.f, -(float)f * (1.f / 32.f));
  float sn, cs;
  sincosf(ang, &sn, &cs);
  float qp = __shfl(qv, lane ^ 32, 64);
  float kp = __shfl(kv, lane ^ 32, 64);
  float qr = (lane < 32) ? (qv * cs + qp * sn) : (-qp * sn + qv * cs);
  float kr = (lane < 32) ? (kv * cs + kp * sn) : (-kp * sn + kv * cs);
  float Kh = expf(ac[h]);
  float sq = qr * qr, sk = kr * kr, sv = vv * vv;
  #pragma unroll
  for (int o = 32; o > 0; o >>= 1) {
    sq += __shfl_xor(sq, o, 64);
    sk += __shfl_xor(sk, o, 64);
    sv += __shfl_xor(sv, o, 64);
  }
  size_t idx = ((size_t)(b * NH + h) * T + t);
  qb[idx * 64 + lane] = f2bf(qr);
  kb[idx * 64 + lane] = f2bf(kr);
  vtb[(size_t)(b * NH + h) * (64 * T) + (size_t)lane * T + t] = f2bf(vv);
  if (lane == 0) {
    q0[idx] = sqrtf(Kh + sq);
    k0[idx] = sqrtf(Kh + sk);
    v0[idx] = sqrtf(Kh + sv);
  }
}

// ---------------- MFMA flash Lorentz attention, split-S, no-max softmax ------
__global__ __launch_bounds__(256) void attn_kernel(
    const ushort_t* __restrict__ qb, const ushort_t* __restrict__ kb,
    const ushort_t* __restrict__ vtb,
    const float* __restrict__ q0, const float* __restrict__ k0,
    const float* __restrict__ v0,
    const float* __restrict__ ac,
    float* __restrict__ Opart, float* __restrict__ lpart,
    float* __restrict__ a0part) {
  __shared__ ushort_t Qs[64 * 64];
  __shared__ ushort_t Ks[64 * 64];
  __shared__ ushort_t Vts[64 * 64];
  __shared__ ushort_t Ps[64 * 72];

  const int sIdx = blockIdx.x;
  const int qtile = (int)gridDim.y - 1 - (int)blockIdx.y;  // heavy first
  const int bh = blockIdx.z;
  const int h = bh % NH;
  const int qt0 = qtile * 64;
  const int tid = threadIdx.x;
  const int w = tid >> 6, lane = tid & 63;
  const int lm = lane & 15, quad = lane >> 4;
  const int wm = w * 16;
  const int sw = lm & 7;

  const int n = qtile + 1;
  const int kbeg = (n * sIdx) / NSPLIT;
  const int kend = (n * (sIdx + 1)) / NSPLIT;
  const size_t pb = (size_t)(sIdx * 48 + bh) * T;

  if (kbeg >= kend) {  // empty split — neutral partial
    #pragma unroll
    for (int r = 0; r < 4; ++r) {
      const int i = qt0 + wm + quad * 4 + r;
      float* orow = Opart + (pb + i) * 64;
      #pragma unroll
      for (int nt = 0; nt < 4; ++nt) orow[nt * 16 + lm] = 0.f;
      if (lm == 0) { lpart[pb + i] = 0.f; a0part[pb + i] = 0.f; }
    }
    return;
  }

  const float Kh = expf(ac[h]);
  const float sqrtK = sqrtf(Kh);
  const float invK = 1.0f / Kh;
  const float nsK = -sqrtK;
  const bool k1 = (Kh == 1.0f);

  {
    const ushort_t* qt = qb + ((size_t)bh * T + qt0) * 64;
    #pragma unroll
    for (int j = 0; j < 2; ++j) {
      int e = (j * 4 + w) * 512 + lane * 8;
      int r = e >> 6, chs = (e >> 3) & 7;
      int clog = (chs ^ (r & 7)) * 8;
      __builtin_amdgcn_global_load_lds(
          (const __attribute__((address_space(1))) void*)(qt + r * 64 + clog),
          (__attribute__((address_space(3))) void*)&Qs[(j * 4 + w) * 512],
          16, 0, 0);
    }
  }
  float q0rv[4];
  #pragma unroll
  for (int r = 0; r < 4; ++r)
    q0rv[r] = q0[(size_t)bh * T + qt0 + wm + quad * 4 + r];

  float lsum[4], a0r[4];
  floatx4 oacc[4];
  #pragma unroll
  for (int r = 0; r < 4; ++r) { lsum[r] = 0.f; a0r[r] = 0.f; }
  #pragma unroll
  for (int nt = 0; nt < 4; ++nt) { floatx4 z = {0.f,0.f,0.f,0.f}; oacc[nt] = z; }

  for (int kt = kbeg; kt < kend; ++kt) {
    const int j0 = kt * 64;
    __syncthreads();
    {
      const ushort_t* ktile = kb + ((size_t)bh * T + j0) * 64;
      const ushort_t* vbh = vtb + (size_t)bh * (64 * T);
      #pragma unroll
      for (int j = 0; j < 2; ++j) {
        int e = (j * 4 + w) * 512 + lane * 8;
        int r = e >> 6, chs = (e >> 3) & 7;
        int clog = (chs ^ (r & 7)) * 8;
        __builtin_amdgcn_global_load_lds(
            (const __attribute__((address_space(1))) void*)(ktile + r * 64 + clog),
            (__attribute__((address_space(3))) void*)&Ks[(j * 4 + w) * 512],
            16, 0, 0);
        __builtin_amdgcn_global_load_lds(
            (const __attribute__((address_space(1))) void*)(vbh + (size_t)r * T + j0 + clog),
            (__attribute__((address_space(3))) void*)&Vts[(j * 4 + w) * 512],
            16, 0, 0);
      }
    }
    float k0i[4], v0v[4];
    #pragma unroll
    for (int jt = 0; jt < 4; ++jt) {
      k0i[jt] = k0[(size_t)bh * T + j0 + jt * 16 + lm] * invK;
      v0v[jt] = v0[(size_t)bh * T + j0 + jt * 16 + lm];
    }
    __syncthreads();

    short8 qf0 = *(const short8*)&Qs[(wm + lm) * 64 + ((0 + quad) ^ sw) * 8];
    short8 qf1 = *(const short8*)&Qs[(wm + lm) * 64 + ((4 + quad) ^ sw) * 8];
    floatx4 sacc[4];
    #pragma unroll
    for (int jt = 0; jt < 4; ++jt) {
      const int krow = jt * 16 + lm;
      short8 kf0 = *(const short8*)&Ks[krow * 64 + ((0 + quad) ^ sw) * 8];
      short8 kf1 = *(const short8*)&Ks[krow * 64 + ((4 + quad) ^ sw) * 8];
      floatx4 z = {0.f, 0.f, 0.f, 0.f};
      z = __builtin_amdgcn_mfma_f32_16x16x32_bf16(qf0, kf0, z, 0, 0, 0);
      z = __builtin_amdgcn_mfma_f32_16x16x32_bf16(qf1, kf1, z, 0, 0, 0);
      sacc[jt] = z;
    }

    const bool diag = (kt == qtile);
    if (k1) {
      #pragma unroll
      for (int r = 0; r < 4; ++r) {
        const int i = qt0 + wm + quad * 4 + r;
        float ls = 0.f, a0s = 0.f;
        #pragma unroll
        for (int jt = 0; jt < 4; ++jt) {
          float c = fmaf(-invK, sacc[jt][r], q0rv[r] * k0i[jt]);
          c = fmaxf(c, 1.000001f);
          float p = c - sqrtf(fmaf(c, c, -1.f));   // exp(-arccosh(c)), K=1
          if (diag && (j0 + jt * 16 + lm > i)) p = 0.f;
          ushort_t pb2 = f2bf(p);
          Ps[(wm + quad * 4 + r) * 72 + jt * 16 + lm] = pb2;
          float pf = bf2f(pb2);
          ls += pf;
          a0s = fmaf(pf, v0v[jt], a0s);
        }
        lsum[r] += ls;
        a0r[r] += a0s;
      }
    } else {
      #pragma unroll
      for (int r = 0; r < 4; ++r) {
        const int i = qt0 + wm + quad * 4 + r;
        float ls = 0.f, a0s = 0.f;
        #pragma unroll
        for (int jt = 0; jt < 4; ++jt) {
          float c = fmaf(-invK, sacc[jt][r], q0rv[r] * k0i[jt]);
          c = fmaxf(c, 1.000001f);
          float z = c + sqrtf(fmaf(c, c, -1.f));
          // p = (c+sqrt(c^2-1))^(-sqrtK); v_log_f32 computes log2
          float p = __builtin_amdgcn_exp2f(nsK * __builtin_amdgcn_logf(z));
          if (diag && (j0 + jt * 16 + lm > i)) p = 0.f;
          ushort_t pb2 = f2bf(p);
          Ps[(wm + quad * 4 + r) * 72 + jt * 16 + lm] = pb2;
          float pf = bf2f(pb2);
          ls += pf;
          a0s = fmaf(pf, v0v[jt], a0s);
        }
        lsum[r] += ls;
        a0r[r] += a0s;
      }
    }

    short8 pf0 = *(const short8*)&Ps[(wm + lm) * 72 + quad * 8];
    short8 pf1 = *(const short8*)&Ps[(wm + lm) * 72 + 32 + quad * 8];
    #pragma unroll
    for (int nt = 0; nt < 4; ++nt) {
      const int vrow = nt * 16 + lm;
      short8 vf0 = *(const short8*)&Vts[vrow * 64 + ((0 + quad) ^ sw) * 8];
      short8 vf1 = *(const short8*)&Vts[vrow * 64 + ((4 + quad) ^ sw) * 8];
      oacc[nt] = __builtin_amdgcn_mfma_f32_16x16x32_bf16(pf0, vf0, oacc[nt], 0, 0, 0);
      oacc[nt] = __builtin_amdgcn_mfma_f32_16x16x32_bf16(pf1, vf1, oacc[nt], 0, 0, 0);
    }
  }

  #pragma unroll
  for (int r = 0; r < 4; ++r) {
    float lf = red16_sum(lsum[r]);
    float a0f = red16_sum(a0r[r]);
    const int i = qt0 + wm + quad * 4 + r;
    float* orow = Opart + (pb + i) * 64;
    #pragma unroll
    for (int nt = 0; nt < 4; ++nt) orow[nt * 16 + lm] = oacc[nt][r];
    if (lm == 0) { lpart[pb + i] = lf; a0part[pb + i] = a0f; }
  }
}

// ---------------- combine split-S partials (plain sums) + Lorentz epilogue ---
__global__ __launch_bounds__(256) void attn_combine(
    const float* __restrict__ Opart, const float* __restrict__ lpart,
    const float* __restrict__ a0part,
    const float* __restrict__ ac, ushort_t* __restrict__ aout) {
  const int widx = blockIdx.x * 4 + (threadIdx.x >> 6);
  const int lane = threadIdx.x & 63;
  const int bh = widx >> 10;
  const int t = widx & 1023;
  const int h = bh % NH, b = bh / NH;
  float L = 0.f, A0 = 0.f, O = 0.f;
  #pragma unroll
  for (int sp = 0; sp < NSPLIT; ++sp) {
    const size_t r = (size_t)(sp * 48 + bh) * T + t;
    L += lpart[r];
    A0 += a0part[r];
    O += Opart[r * 64 + lane];
  }
  const float invl = 1.f / L;
  float av = O * invl;
  float ssq = av * av;
  #pragma unroll
  for (int o = 32; o > 0; o >>= 1) ssq += __shfl_xor(ssq, o, 64);
  float a0n = A0 * invl;
  float nsq = fmaxf(a0n * a0n - ssq, 1e-6f);
  float Kh = expf(ac[h]);
  float scale = sqrtf(Kh) * rsqrtf(nsq);
  ushort_t* orow = aout + (size_t)(b * T + t) * KPA + h * 65;
  orow[1 + lane] = f2bf(av * scale);
  if (lane == 0) orow[0] = f2bf(a0n * scale);
}

// ---------------- exact gelu + project: bf16 in (stride NEXP) -> bf16 --------
__global__ __launch_bounds__(256) void gelu_project(
    const ushort_t* __restrict__ hsrc, const float* __restrict__ curv,
    ushort_t* __restrict__ hp) {
  __shared__ float sm[4];
  const int row = blockIdx.x;
  const int tid = threadIdx.x;
  const ushort_t* hr = hsrc + (size_t)row * NEXP;
  float gv[13];
  float ss = 0.f;
  #pragma unroll
  for (int i = 0; i < 13; ++i) {
    int c = tid + 256 * i;
    float xx = (c < HEXP) ? bf2f(hr[c]) : 0.f;
    float gg = 0.5f * xx * (1.f + erff(xx * 0.70710678118654752f));
    gv[i] = gg; ss += gg * gg;
  }
  ss = blk_reduce_sum(ss, sm);
  float tc = sqrtf(expf(curv[0]) + ss);
  ushort_t* orow = hp + (size_t)row * KPB;
  #pragma unroll
  for (int i = 0; i < 13; ++i) {
    int c = tid + 256 * i;
    if (c < HEXP) orow[1 + c] = f2bf(gv[i]);
  }
  if (tid == 0) orow[0] = f2bf(tc);
  if (tid < KPB - (HEXP + 1)) orow[HEXP + 1 + tid] = 0;
}

// ------- fused: split-K reduce + bias + residual -> x2, then LN+project ------
__global__ __launch_bounds__(256) void reduce_ln_project(
    const float* __restrict__ Cp, int nsplit,
    const float* __restrict__ bias, const float* __restrict__ res,
    float* __restrict__ x2out,
    const float* __restrict__ g, const float* __restrict__ bb,
    const float* __restrict__ curv, ushort_t* __restrict__ lnp) {
  __shared__ float sm[4];
  const int row = blockIdx.x;
  const int tid = threadIdx.x;
  float xv[3];
  float s = 0.f, ss = 0.f;
  #pragma unroll
  for (int i = 0; i < 3; ++i) {
    const int c = tid + 256 * i;
    float v = bias[c] + res[(size_t)row * NE + c];
    for (int sp = 0; sp < nsplit; ++sp)
      v += Cp[(size_t)sp * ROWS * NE + (size_t)row * NE + c];
    x2out[(size_t)row * NE + c] = v;
    xv[i] = v;
    s += v; ss += v * v;
  }
  s = blk_reduce_sum(s, sm);
  ss = blk_reduce_sum(ss, sm);
  float mean = s * (1.f / 768.f);
  float var = ss * (1.f / 768.f) - mean * mean;
  float rstd = rsqrtf(var + 1e-5f);
  float yv[3]; float ys = 0.f;
  #pragma unroll
  for (int i = 0; i < 3; ++i) {
    int c = tid + 256 * i;
    yv[i] = (xv[i] - mean) * rstd * g[c] + bb[c];
    ys += yv[i] * yv[i];
  }
  ys = blk_reduce_sum(ys, sm);
  float tc = sqrtf(expf(curv[0]) + ys);
  ushort_t* orow = lnp + (size_t)row * KPA;
  #pragma unroll
  for (int i = 0; i < 3; ++i) orow[1 + tid + 256 * i] = f2bf(yv[i]);
  if (tid == 0) orow[0] = f2bf(tc);
  if (tid < KPA - 769) orow[769 + tid] = 0;
}

// ------- fused: split-K reduce + bias + residual + final project -> out ------
__global__ __launch_bounds__(256) void reduce_final_project(
    const float* __restrict__ Cp, int nsplit,
    const float* __restrict__ bias, const float* __restrict__ res,
    const float* __restrict__ curv, float* __restrict__ out) {
  __shared__ float sm[4];
  const int row = blockIdx.x;
  const int tid = threadIdx.x;
  float v[3]; float ss = 0.f;
  #pragma unroll
  for (int i = 0; i < 3; ++i) {
    const int c = tid + 256 * i;
    float t = bias[c] + res[(size_t)row * NE + c];
    for (int sp = 0; sp < nsplit; ++sp)
      t += Cp[(size_t)sp * ROWS * NE + (size_t)row * NE + c];
    v[i] = t; ss += t * t;
  }
  ss = blk_reduce_sum(ss, sm);
  float tc = sqrtf(expf(curv[0]) + ss);
  float* o = out + (size_t)row * 769;
  #pragma unroll
  for (int i = 0; i < 3; ++i) o[1 + tid + 256 * i] = v[i];
  if (tid == 0) o[0] = tc;
}

// ---------------- launcher ----------------
extern "C" void kernel_launch(void* const* d_in, const int* in_sizes, int n_in,
                              void* d_out, int out_size, void* d_ws, size_t ws_size,
                              hipStream_t stream) {
  (void)in_sizes; (void)n_in; (void)out_size; (void)ws_size;
  const float* x     = (const float*)d_in[0];
  const float* bc    = (const float*)d_in[1];
  const float* mc    = (const float*)d_in[2];
  const float* ac    = (const float*)d_in[3];
  const float* qkvw  = (const float*)d_in[4];
  const float* projw = (const float*)d_in[5];
  const float* projb = (const float*)d_in[6];
  const float* expw  = (const float*)d_in[7];
  const float* expb  = (const float*)d_in[8];
  const float* shrw  = (const float*)d_in[9];
  const float* shrb  = (const float*)d_in[10];
  const float* lng   = (const float*)d_in[11];
  const float* lnb   = (const float*)d_in[12];
  float* out = (float*)d_out;

  // ---- workspace layout (~144 MB worst phase; 169 MB verified available) ----
  float* x2 = (float*)d_ws;                                  // 4096*768 f32
  ushort_t* qkv_wb  = (ushort_t*)(x2 + (size_t)ROWS * NE);   // 2304*832 bf16
  ushort_t* proj_wb = qkv_wb + (size_t)2304 * KPA;           // 768*832
  ushort_t* exp_wb  = proj_wb + (size_t)768 * KPA;           // 3200*832
  ushort_t* shr_wb  = exp_wb + (size_t)NEXP * KPA;           // 768*3136
  ushort_t* lnp_bf  = shr_wb + (size_t)768 * KPB;            // 4096*832
  ushort_t* aout_bf = lnp_bf + (size_t)ROWS * KPA;           // 4096*832
  char* r2 = (char*)(aout_bf + (size_t)ROWS * KPA);
  // r2 union #1 (attn phase): bf16 qkv + bf16 q/k/vt + time comps + partials
  ushort_t* qkvb = (ushort_t*)r2;                            // ROWS*2304 bf16
  ushort_t* qbb = qkvb + (size_t)ROWS * 2304;
  ushort_t* kbb = qbb + (size_t)48 * T * 64;
  ushort_t* vtb = kbb + (size_t)48 * T * 64;
  float* q0b = (float*)(vtb + (size_t)48 * T * 64);
  float* k0b = q0b + (size_t)48 * T;
  float* v0b = k0b + (size_t)48 * T;
  float* Opart = v0b + (size_t)48 * T;                       // NSPLIT*48*1024*64 f32
  float* lpart = Opart + (size_t)NSPLIT * 48 * T * 64;
  float* a0part = lpart + (size_t)NSPLIT * 48 * T;
  // proj split-K partials (alias r2 front — qkv/q/k dead by then; partials
  // need 25.2MB, Opart region starts at +31.5MB: no overlap)
  float* ppartP = (float*)r2;                                // 2*ROWS*768 f32
  // r2 union #2 (mlp phase)
  ushort_t* hbbf = (ushort_t*)r2;                            // ROWS*NEXP bf16
  ushort_t* hp_bf = hbbf + (size_t)ROWS * NEXP;              // ROWS*KPB bf16
  float* ppartS = (float*)(hp_bf + (size_t)ROWS * KPB);      // 4*ROWS*768 f32

  // 0. merged weight conversions + pad zero
  prep_kernel<<<NB_A + NB_B + NB_C + NB_D + NB_E, 256, 0, stream>>>(
      qkv_wb, qkvw, proj_wb, projw, exp_wb, expw, shr_wb, shrw, aout_bf);
  // 1. block_norm(lx) -> bf16
  ln_project<<<ROWS, 256, 0, stream>>>(x, lng, lnb, bc, lnp_bf);
  // 2. qkv = ln1p @ qkv_w^T  (bf16 out)
  gemm_bf16<<<dim3(2304 / 128, ROWS / 128, 1), 256, 0, stream>>>(
      lnp_bf, KPA, qkv_wb, KPA, qkvb, 2304, KPA / 64, KPA / 64,
      nullptr, 0, nullptr, 0, 1, nullptr);
  // 3. rotary + per-head project -> bf16 (V transposed)
  rope_project<<<(ROWS * NH) / 4, 256, 0, stream>>>(qkvb, ac, qbb, kbb, vtb, q0b, k0b, v0b);
  // 4. split-S MFMA Lorentz flash attention -> partials, then combine
  attn_kernel<<<dim3(NSPLIT, T / 64, 48), 256, 0, stream>>>(
      qbb, kbb, vtb, q0b, k0b, v0b, ac, Opart, lpart, a0part);
  attn_combine<<<(48 * T) / 4, 256, 0, stream>>>(Opart, lpart, a0part, ac, aout_bf);
  // 5+6. attn proj split-K=2, fused reduce(+bias+res x)+LN+project
  gemm_bf16<<<dim3(768 / 128, ROWS / 128, 2), 256, 0, stream>>>(
      aout_bf, KPA, proj_wb, KPA, nullptr, NE, KPA / 64, 7,
      nullptr, 0, nullptr, 0, 0, ppartP);
  reduce_ln_project<<<ROWS, 256, 0, stream>>>(
      ppartP, 2, projb, x, x2, lng, lnb, bc, lnp_bf);
  // 7. mlp expand + bias (bf16 out)
  gemm_bf16<<<dim3(NEXP / 128, ROWS / 128, 1), 256, 0, stream>>>(
      lnp_bf, KPA, exp_wb, KPA, hbbf, NEXP, KPA / 64, KPA / 64,
      expb, HEXP, nullptr, 0, 1, nullptr);
  // 8. gelu + project -> bf16
  gelu_project<<<ROWS, 256, 0, stream>>>(hbbf, mc, hp_bf);
  // 9+10. mlp shrink split-K=4, fused reduce(+bias+res x2)+final project
  gemm_bf16<<<dim3(768 / 128, ROWS / 128, 4), 256, 0, stream>>>(
      hp_bf, KPB, shr_wb, KPB, nullptr, NE, KPB / 64, 13,
      nullptr, 0, nullptr, 0, 0, ppartS);
  reduce_final_project<<<ROWS, 256, 0, stream>>>(
      ppartS, 4, shrb, x2, bc, out);
}

// Round 11
// 376.141 us; speedup vs baseline: 1.0235x; 1.0235x over previous
//
#include <hip/hip_runtime.h>
#include <cmath>

typedef unsigned short ushort_t;
typedef __attribute__((ext_vector_type(8))) short short8;
typedef __attribute__((ext_vector_type(4))) float floatx4;

// Problem constants
#define NH    12
#define T     1024
#define ROWS  4096      // B*T
#define NE    768
#define KPA   832       // bf16 K-pad for 769/780 (multiple of 64)
#define KPB   3136      // bf16 K-pad for 3076 (multiple of 64)
#define NEXP  3200      // padded expand N (3075 -> 25*128)
#define HEXP  3075
#define NSPLIT 3        // attention split-S factor

// ---------------- helpers ----------------
__device__ __forceinline__ ushort_t f2bf(float f) {
  union { float f; unsigned u; } v; v.f = f;
  unsigned r = v.u + 0x7fffu + ((v.u >> 16) & 1u);
  return (ushort_t)(r >> 16);
}
__device__ __forceinline__ ushort_t f2bf_trunc(float f) {
  union { float f; unsigned u; } v; v.f = f;
  return (ushort_t)(v.u >> 16);
}
__device__ __forceinline__ float bf2f(ushort_t b) {
  union { unsigned u; float f; } v; v.u = ((unsigned)b) << 16;
  return v.f;
}
__device__ __forceinline__ float blk_reduce_sum(float v, float* sm) {
  #pragma unroll
  for (int o = 32; o > 0; o >>= 1) v += __shfl_xor(v, o, 64);
  int lane = threadIdx.x & 63, w = threadIdx.x >> 6;
  __syncthreads();
  if (lane == 0) sm[w] = v;
  __syncthreads();
  return sm[0] + sm[1] + sm[2] + sm[3];
}
__device__ __forceinline__ float red16_sum(float v) {
  #pragma unroll
  for (int o = 1; o < 16; o <<= 1) v += __shfl_xor(v, o, 64);
  return v;
}

// ------ merged prep: 4 weight pad-converts + aout pad zero + LN#1 -----------
#define NB_A 7488    // 2304*832/256
#define NB_B 2496    // 768*832/256
#define NB_C 10400   // 3200*832/256
#define NB_D 9408    // 768*3136/256
#define NB_E 16      // ROWS/256
__device__ __forceinline__ void cvt_elem(ushort_t* __restrict__ dst,
                                         const float* __restrict__ src,
                                         int idx, int srcRows, int srcK, int dstK) {
  int r = idx / dstK, c = idx - r * dstK;
  dst[idx] = (r < srcRows && c < srcK) ? f2bf(src[(size_t)r * srcK + c]) : (ushort_t)0;
}
__global__ __launch_bounds__(256) void prep_kernel(
    ushort_t* __restrict__ qkv_wb, const float* __restrict__ qkvw,
    ushort_t* __restrict__ proj_wb, const float* __restrict__ projw,
    ushort_t* __restrict__ exp_wb, const float* __restrict__ expw,
    ushort_t* __restrict__ shr_wb, const float* __restrict__ shrw,
    ushort_t* __restrict__ aout_bf,
    const float* __restrict__ xin, const float* __restrict__ g,
    const float* __restrict__ bb, const float* __restrict__ curv,
    ushort_t* __restrict__ lnp) {
  __shared__ float sm[4];
  int blk = blockIdx.x;
  int tid = threadIdx.x;
  if (blk < NB_A) {
    cvt_elem(qkv_wb, qkvw, blk * 256 + tid, 2304, 769, KPA);
  } else if (blk < NB_A + NB_B) {
    cvt_elem(proj_wb, projw, (blk - NB_A) * 256 + tid, 768, 780, KPA);
  } else if (blk < NB_A + NB_B + NB_C) {
    cvt_elem(exp_wb, expw, (blk - NB_A - NB_B) * 256 + tid, HEXP, 769, KPA);
  } else if (blk < NB_A + NB_B + NB_C + NB_D) {
    cvt_elem(shr_wb, shrw, (blk - NB_A - NB_B - NB_C) * 256 + tid, 768, 3076, KPB);
  } else if (blk < NB_A + NB_B + NB_C + NB_D + NB_E) {
    int r = (blk - NB_A - NB_B - NB_C - NB_D) * 256 + tid;
    ushort_t* p = aout_bf + (size_t)r * KPA + 780;
    #pragma unroll
    for (int j = 0; j < KPA - 780; ++j) p[j] = 0;
  } else {
    // layernorm + project row
    const int row = blk - (NB_A + NB_B + NB_C + NB_D + NB_E);
    const float* xr = xin + (size_t)row * NE;
    float xv[3];
    float s = 0.f, ss = 0.f;
    #pragma unroll
    for (int i = 0; i < 3; ++i) {
      xv[i] = xr[tid + 256 * i];
      s += xv[i]; ss += xv[i] * xv[i];
    }
    s = blk_reduce_sum(s, sm);
    ss = blk_reduce_sum(ss, sm);
    float mean = s * (1.f / 768.f);
    float var = ss * (1.f / 768.f) - mean * mean;
    float rstd = rsqrtf(var + 1e-5f);
    float yv[3]; float ys = 0.f;
    #pragma unroll
    for (int i = 0; i < 3; ++i) {
      int c = tid + 256 * i;
      yv[i] = (xv[i] - mean) * rstd * g[c] + bb[c];
      ys += yv[i] * yv[i];
    }
    ys = blk_reduce_sum(ys, sm);
    float tc = sqrtf(expf(curv[0]) + ys);
    ushort_t* orow = lnp + (size_t)row * KPA;
    #pragma unroll
    for (int i = 0; i < 3; ++i) orow[1 + tid + 256 * i] = f2bf(yv[i]);
    if (tid == 0) orow[0] = f2bf(tc);
    if (tid < KPA - 769) orow[769 + tid] = 0;
  }
}

// ---------------- bf16 MFMA NT GEMM, BK=64, swizzled LDS, optional split-K ---
// split-K partials stored as bf16.
__global__ __launch_bounds__(256) void gemm_bf16(
    const ushort_t* __restrict__ A, int lda,
    const ushort_t* __restrict__ W, int ldw,
    void* __restrict__ Cout, int ldc,
    int nkTot, int cpt,
    const float* __restrict__ bias, int biasN,
    const float* __restrict__ res, int ldres,
    int outMode, void* __restrict__ Cp) {
  __shared__ ushort_t As[128 * 64];
  __shared__ ushort_t Bs[128 * 64];
  const int tid = threadIdx.x;
  const int w = tid >> 6, lane = tid & 63;
  const int rowBase = (int)blockIdx.y << 7;
  const int colBase = (int)blockIdx.x << 7;
  const int wm = (w & 1) * 64, wn = (w >> 1) * 64;
  const int lm = lane & 15, quad = lane >> 4;
  const int p0 = quad ^ (lm & 7);   // fragment-read chunk position, s=0

  floatx4 acc[4][4];
  #pragma unroll
  for (int i = 0; i < 4; ++i)
    #pragma unroll
    for (int j = 0; j < 4; ++j) {
      floatx4 z = {0.f, 0.f, 0.f, 0.f};
      acc[i][j] = z;
    }

  const int kt0 = (int)blockIdx.z * cpt;
  const int kt1 = min(nkTot, kt0 + cpt);
  for (int kt = kt0; kt < kt1; ++kt) {
    __syncthreads();
    #pragma unroll
    for (int j = 0; j < 4; ++j) {
      int ci = j * 256 + tid;            // 16B chunk index 0..1023
      int r = ci >> 3;                   // row 0..127
      int g = (ci & 7) ^ (r & 7);        // global chunk stored at this position
      const ushort_t* ga = A + (size_t)(rowBase + r) * lda + kt * 64 + g * 8;
      const ushort_t* gb = W + (size_t)(colBase + r) * ldw + kt * 64 + g * 8;
      __builtin_amdgcn_global_load_lds(
          (const __attribute__((address_space(1))) void*)ga,
          (__attribute__((address_space(3))) void*)&As[(j * 256 + w * 64) * 8],
          16, 0, 0);
      __builtin_amdgcn_global_load_lds(
          (const __attribute__((address_space(1))) void*)gb,
          (__attribute__((address_space(3))) void*)&Bs[(j * 256 + w * 64) * 8],
          16, 0, 0);
    }
    __syncthreads();

    #pragma unroll
    for (int s = 0; s < 2; ++s) {
      const int ps = s ? (p0 ^ 4) : p0;
      short8 af[4], bfr[4];
      #pragma unroll
      for (int i = 0; i < 4; ++i) {
        af[i]  = *(const short8*)&As[(wm + i * 16 + lm) * 64 + ps * 8];
        bfr[i] = *(const short8*)&Bs[(wn + i * 16 + lm) * 64 + ps * 8];
      }
      #pragma unroll
      for (int i = 0; i < 4; ++i)
        #pragma unroll
        for (int jn = 0; jn < 4; ++jn)
          acc[i][jn] = __builtin_amdgcn_mfma_f32_16x16x32_bf16(
              af[i], bfr[jn], acc[i][jn], 0, 0, 0);
    }
  }

  if (gridDim.z > 1) {
    ushort_t* dst = (ushort_t*)Cp + (size_t)blockIdx.z * ROWS * ldc;
    #pragma unroll
    for (int i = 0; i < 4; ++i)
      #pragma unroll
      for (int jn = 0; jn < 4; ++jn) {
        const int col = colBase + wn + jn * 16 + lm;
        #pragma unroll
        for (int rg = 0; rg < 4; ++rg) {
          const int row = rowBase + wm + i * 16 + quad * 4 + rg;
          dst[(size_t)row * ldc + col] = f2bf(acc[i][jn][rg]);
        }
      }
  } else if (outMode == 1) {
    ushort_t* C = (ushort_t*)Cout;
    #pragma unroll
    for (int i = 0; i < 4; ++i)
      #pragma unroll
      for (int jn = 0; jn < 4; ++jn) {
        const int col = colBase + wn + jn * 16 + lm;
        const float bv = bias ? ((col < biasN) ? bias[col] : 0.f) : 0.f;
        #pragma unroll
        for (int rg = 0; rg < 4; ++rg) {
          const int row = rowBase + wm + i * 16 + quad * 4 + rg;
          C[(size_t)row * ldc + col] = f2bf(acc[i][jn][rg] + bv);
        }
      }
  } else {
    float* C = (float*)Cout;
    #pragma unroll
    for (int i = 0; i < 4; ++i)
      #pragma unroll
      for (int jn = 0; jn < 4; ++jn) {
        const int col = colBase + wn + jn * 16 + lm;
        const float bv = bias ? ((col < biasN) ? bias[col] : 0.f) : 0.f;
        #pragma unroll
        for (int rg = 0; rg < 4; ++rg) {
          const int row = rowBase + wm + i * 16 + quad * 4 + rg;
          float o = acc[i][jn][rg] + bv;
          if (res) o += res[(size_t)row * ldres + col];
          C[(size_t)row * ldc + col] = o;
        }
      }
  }
}

// ---------------- rotary + per-head hyperboloid project (bf16 in) ------------
__global__ __launch_bounds__(256) void rope_project(
    const ushort_t* __restrict__ qkv, const float* __restrict__ ac,
    ushort_t* __restrict__ qb, ushort_t* __restrict__ kb, ushort_t* __restrict__ vtb,
    float* __restrict__ q0, float* __restrict__ k0, float* __restrict__ v0) {
  int gid = blockIdx.x * 4 + (threadIdx.x >> 6);
  int lane = threadIdx.x & 63;
  int h = gid % NH;
  int bt = gid / NH;
  int t = bt & (T - 1);
  int b = bt >> 10;
  size_t base = (size_t)bt * 2304 + h * 64;
  float qv = bf2f(qkv[base + lane]);
  float kv = bf2f(qkv[base + 768 + lane]);
  float vv = bf2f(qkv[base + 1536 + lane]);
  int f = lane & 31;
  float ang = (float)t * powf(10000.f, -(float)f * (1.f / 32.f));
  float sn, cs;
  sincosf(ang, &sn, &cs);
  float qp = __shfl(qv, lane ^ 32, 64);
  float kp = __shfl(kv, lane ^ 32, 64);
  float qr = (lane < 32) ? (qv * cs + qp * sn) : (-qp * sn + qv * cs);
  float kr = (lane < 32) ? (kv * cs + kp * sn) : (-kp * sn + kv * cs);
  float Kh = expf(ac[h]);
  float sq = qr * qr, sk = kr * kr, sv = vv * vv;
  #pragma unroll
  for (int o = 32; o > 0; o >>= 1) {
    sq += __shfl_xor(sq, o, 64);
    sk += __shfl_xor(sk, o, 64);
    sv += __shfl_xor(sv, o, 64);
  }
  size_t idx = ((size_t)(b * NH + h) * T + t);
  qb[idx * 64 + lane] = f2bf(qr);
  kb[idx * 64 + lane] = f2bf(kr);
  vtb[(size_t)(b * NH + h) * (64 * T) + (size_t)lane * T + t] = f2bf(vv);
  if (lane == 0) {
    q0[idx] = sqrtf(Kh + sq);
    k0[idx] = sqrtf(Kh + sk);
    v0[idx] = sqrtf(Kh + sv);
  }
}

// ---------------- MFMA flash Lorentz attention, split-S, no-max softmax ------
// bf16 O-partials; truncating P round (consistent num/denom -> error cancels).
__global__ __launch_bounds__(256) void attn_kernel(
    const ushort_t* __restrict__ qb, const ushort_t* __restrict__ kb,
    const ushort_t* __restrict__ vtb,
    const float* __restrict__ q0, const float* __restrict__ k0,
    const float* __restrict__ v0,
    const float* __restrict__ ac,
    ushort_t* __restrict__ Opart, float* __restrict__ lpart,
    float* __restrict__ a0part) {
  __shared__ ushort_t Qs[64 * 64];
  __shared__ ushort_t Ks[64 * 64];
  __shared__ ushort_t Vts[64 * 64];
  __shared__ ushort_t Ps[64 * 72];

  const int sIdx = blockIdx.x;
  const int qtile = (int)gridDim.y - 1 - (int)blockIdx.y;  // heavy first
  const int bh = blockIdx.z;
  const int h = bh % NH;
  const int qt0 = qtile * 64;
  const int tid = threadIdx.x;
  const int w = tid >> 6, lane = tid & 63;
  const int lm = lane & 15, quad = lane >> 4;
  const int wm = w * 16;
  const int sw = lm & 7;

  const int n = qtile + 1;
  const int kbeg = (n * sIdx) / NSPLIT;
  const int kend = (n * (sIdx + 1)) / NSPLIT;
  const size_t pb = (size_t)(sIdx * 48 + bh) * T;

  if (kbeg >= kend) {  // empty split — neutral partial
    #pragma unroll
    for (int r = 0; r < 4; ++r) {
      const int i = qt0 + wm + quad * 4 + r;
      ushort_t* orow = Opart + (pb + i) * 64;
      #pragma unroll
      for (int nt = 0; nt < 4; ++nt) orow[nt * 16 + lm] = 0;
      if (lm == 0) { lpart[pb + i] = 0.f; a0part[pb + i] = 0.f; }
    }
    return;
  }

  const float Kh = expf(ac[h]);
  const float sqrtK = sqrtf(Kh);
  const float invK = 1.0f / Kh;
  const float nsK = -sqrtK;
  const bool k1 = (Kh == 1.0f);

  {
    const ushort_t* qt = qb + ((size_t)bh * T + qt0) * 64;
    #pragma unroll
    for (int j = 0; j < 2; ++j) {
      int e = (j * 4 + w) * 512 + lane * 8;
      int r = e >> 6, chs = (e >> 3) & 7;
      int clog = (chs ^ (r & 7)) * 8;
      __builtin_amdgcn_global_load_lds(
          (const __attribute__((address_space(1))) void*)(qt + r * 64 + clog),
          (__attribute__((address_space(3))) void*)&Qs[(j * 4 + w) * 512],
          16, 0, 0);
    }
  }
  __syncthreads();   // Q tile resident
  // hoisted loop-invariant Q fragments
  short8 qf0 = *(const short8*)&Qs[(wm + lm) * 64 + ((0 + quad) ^ sw) * 8];
  short8 qf1 = *(const short8*)&Qs[(wm + lm) * 64 + ((4 + quad) ^ sw) * 8];
  float q0rv[4];
  #pragma unroll
  for (int r = 0; r < 4; ++r)
    q0rv[r] = q0[(size_t)bh * T + qt0 + wm + quad * 4 + r];

  float lsum[4], a0r[4];
  floatx4 oacc[4];
  #pragma unroll
  for (int r = 0; r < 4; ++r) { lsum[r] = 0.f; a0r[r] = 0.f; }
  #pragma unroll
  for (int nt = 0; nt < 4; ++nt) { floatx4 z = {0.f,0.f,0.f,0.f}; oacc[nt] = z; }

  for (int kt = kbeg; kt < kend; ++kt) {
    const int j0 = kt * 64;
    __syncthreads();
    {
      const ushort_t* ktile = kb + ((size_t)bh * T + j0) * 64;
      const ushort_t* vbh = vtb + (size_t)bh * (64 * T);
      #pragma unroll
      for (int j = 0; j < 2; ++j) {
        int e = (j * 4 + w) * 512 + lane * 8;
        int r = e >> 6, chs = (e >> 3) & 7;
        int clog = (chs ^ (r & 7)) * 8;
        __builtin_amdgcn_global_load_lds(
            (const __attribute__((address_space(1))) void*)(ktile + r * 64 + clog),
            (__attribute__((address_space(3))) void*)&Ks[(j * 4 + w) * 512],
            16, 0, 0);
        __builtin_amdgcn_global_load_lds(
            (const __attribute__((address_space(1))) void*)(vbh + (size_t)r * T + j0 + clog),
            (__attribute__((address_space(3))) void*)&Vts[(j * 4 + w) * 512],
            16, 0, 0);
      }
    }
    float k0i[4], v0v[4];
    #pragma unroll
    for (int jt = 0; jt < 4; ++jt) {
      k0i[jt] = k0[(size_t)bh * T + j0 + jt * 16 + lm] * invK;
      v0v[jt] = v0[(size_t)bh * T + j0 + jt * 16 + lm];
    }
    __syncthreads();

    floatx4 sacc[4];
    #pragma unroll
    for (int jt = 0; jt < 4; ++jt) {
      const int krow = jt * 16 + lm;
      short8 kf0 = *(const short8*)&Ks[krow * 64 + ((0 + quad) ^ sw) * 8];
      short8 kf1 = *(const short8*)&Ks[krow * 64 + ((4 + quad) ^ sw) * 8];
      floatx4 z = {0.f, 0.f, 0.f, 0.f};
      z = __builtin_amdgcn_mfma_f32_16x16x32_bf16(qf0, kf0, z, 0, 0, 0);
      z = __builtin_amdgcn_mfma_f32_16x16x32_bf16(qf1, kf1, z, 0, 0, 0);
      sacc[jt] = z;
    }

    const bool diag = (kt == qtile);
    if (k1) {
      #pragma unroll
      for (int r = 0; r < 4; ++r) {
        const int i = qt0 + wm + quad * 4 + r;
        float ls = 0.f, a0s = 0.f;
        #pragma unroll
        for (int jt = 0; jt < 4; ++jt) {
          float c = fmaf(-invK, sacc[jt][r], q0rv[r] * k0i[jt]);
          c = fmaxf(c, 1.000001f);
          float p = c - sqrtf(fmaf(c, c, -1.f));   // exp(-arccosh(c)), K=1
          if (diag && (j0 + jt * 16 + lm > i)) p = 0.f;
          ushort_t pb2 = f2bf_trunc(p);
          Ps[(wm + quad * 4 + r) * 72 + jt * 16 + lm] = pb2;
          float pf = bf2f(pb2);
          ls += pf;
          a0s = fmaf(pf, v0v[jt], a0s);
        }
        lsum[r] += ls;
        a0r[r] += a0s;
      }
    } else {
      #pragma unroll
      for (int r = 0; r < 4; ++r) {
        const int i = qt0 + wm + quad * 4 + r;
        float ls = 0.f, a0s = 0.f;
        #pragma unroll
        for (int jt = 0; jt < 4; ++jt) {
          float c = fmaf(-invK, sacc[jt][r], q0rv[r] * k0i[jt]);
          c = fmaxf(c, 1.000001f);
          float z = c + sqrtf(fmaf(c, c, -1.f));
          // p = (c+sqrt(c^2-1))^(-sqrtK); v_log_f32 computes log2
          float p = __builtin_amdgcn_exp2f(nsK * __builtin_amdgcn_logf(z));
          if (diag && (j0 + jt * 16 + lm > i)) p = 0.f;
          ushort_t pb2 = f2bf_trunc(p);
          Ps[(wm + quad * 4 + r) * 72 + jt * 16 + lm] = pb2;
          float pf = bf2f(pb2);
          ls += pf;
          a0s = fmaf(pf, v0v[jt], a0s);
        }
        lsum[r] += ls;
        a0r[r] += a0s;
      }
    }

    short8 pf0 = *(const short8*)&Ps[(wm + lm) * 72 + quad * 8];
    short8 pf1 = *(const short8*)&Ps[(wm + lm) * 72 + 32 + quad * 8];
    #pragma unroll
    for (int nt = 0; nt < 4; ++nt) {
      const int vrow = nt * 16 + lm;
      short8 vf0 = *(const short8*)&Vts[vrow * 64 + ((0 + quad) ^ sw) * 8];
      short8 vf1 = *(const short8*)&Vts[vrow * 64 + ((4 + quad) ^ sw) * 8];
      oacc[nt] = __builtin_amdgcn_mfma_f32_16x16x32_bf16(pf0, vf0, oacc[nt], 0, 0, 0);
      oacc[nt] = __builtin_amdgcn_mfma_f32_16x16x32_bf16(pf1, vf1, oacc[nt], 0, 0, 0);
    }
  }

  #pragma unroll
  for (int r = 0; r < 4; ++r) {
    float lf = red16_sum(lsum[r]);
    float a0f = red16_sum(a0r[r]);
    const int i = qt0 + wm + quad * 4 + r;
    ushort_t* orow = Opart + (pb + i) * 64;
    #pragma unroll
    for (int nt = 0; nt < 4; ++nt) orow[nt * 16 + lm] = f2bf(oacc[nt][r]);
    if (lm == 0) { lpart[pb + i] = lf; a0part[pb + i] = a0f; }
  }
}

// ---------------- combine split-S partials (plain sums) + Lorentz epilogue ---
__global__ __launch_bounds__(256) void attn_combine(
    const ushort_t* __restrict__ Opart, const float* __restrict__ lpart,
    const float* __restrict__ a0part,
    const float* __restrict__ ac, ushort_t* __restrict__ aout) {
  const int widx = blockIdx.x * 4 + (threadIdx.x >> 6);
  const int lane = threadIdx.x & 63;
  const int bh = widx >> 10;
  const int t = widx & 1023;
  const int h = bh % NH, b = bh / NH;
  float L = 0.f, A0 = 0.f, O = 0.f;
  #pragma unroll
  for (int sp = 0; sp < NSPLIT; ++sp) {
    const size_t r = (size_t)(sp * 48 + bh) * T + t;
    L += lpart[r];
    A0 += a0part[r];
    O += bf2f(Opart[r * 64 + lane]);
  }
  const float invl = 1.f / L;
  float av = O * invl;
  float ssq = av * av;
  #pragma unroll
  for (int o = 32; o > 0; o >>= 1) ssq += __shfl_xor(ssq, o, 64);
  float a0n = A0 * invl;
  float nsq = fmaxf(a0n * a0n - ssq, 1e-6f);
  float Kh = expf(ac[h]);
  float scale = sqrtf(Kh) * rsqrtf(nsq);
  ushort_t* orow = aout + (size_t)(b * T + t) * KPA + h * 65;
  orow[1 + lane] = f2bf(av * scale);
  if (lane == 0) orow[0] = f2bf(a0n * scale);
}

// ---------------- exact gelu + project: bf16 in (stride NEXP) -> bf16 --------
__global__ __launch_bounds__(256) void gelu_project(
    const ushort_t* __restrict__ hsrc, const float* __restrict__ curv,
    ushort_t* __restrict__ hp) {
  __shared__ float sm[4];
  const int row = blockIdx.x;
  const int tid = threadIdx.x;
  const ushort_t* hr = hsrc + (size_t)row * NEXP;
  float gv[13];
  float ss = 0.f;
  #pragma unroll
  for (int i = 0; i < 13; ++i) {
    int c = tid + 256 * i;
    float xx = (c < HEXP) ? bf2f(hr[c]) : 0.f;
    float gg = 0.5f * xx * (1.f + erff(xx * 0.70710678118654752f));
    gv[i] = gg; ss += gg * gg;
  }
  ss = blk_reduce_sum(ss, sm);
  float tc = sqrtf(expf(curv[0]) + ss);
  ushort_t* orow = hp + (size_t)row * KPB;
  #pragma unroll
  for (int i = 0; i < 13; ++i) {
    int c = tid + 256 * i;
    if (c < HEXP) orow[1 + c] = f2bf(gv[i]);
  }
  if (tid == 0) orow[0] = f2bf(tc);
  if (tid < KPB - (HEXP + 1)) orow[HEXP + 1 + tid] = 0;
}

// ------- fused: bf16 split-K reduce + bias + residual -> x2, then LN+project -
__global__ __launch_bounds__(256) void reduce_ln_project(
    const ushort_t* __restrict__ Cp, int nsplit,
    const float* __restrict__ bias, const float* __restrict__ res,
    float* __restrict__ x2out,
    const float* __restrict__ g, const float* __restrict__ bb,
    const float* __restrict__ curv, ushort_t* __restrict__ lnp) {
  __shared__ float sm[4];
  const int row = blockIdx.x;
  const int tid = threadIdx.x;
  float xv[3];
  float s = 0.f, ss = 0.f;
  #pragma unroll
  for (int i = 0; i < 3; ++i) {
    const int c = tid + 256 * i;
    float v = bias[c] + res[(size_t)row * NE + c];
    for (int sp = 0; sp < nsplit; ++sp)
      v += bf2f(Cp[(size_t)sp * ROWS * NE + (size_t)row * NE + c]);
    x2out[(size_t)row * NE + c] = v;
    xv[i] = v;
    s += v; ss += v * v;
  }
  s = blk_reduce_sum(s, sm);
  ss = blk_reduce_sum(ss, sm);
  float mean = s * (1.f / 768.f);
  float var = ss * (1.f / 768.f) - mean * mean;
  float rstd = rsqrtf(var + 1e-5f);
  float yv[3]; float ys = 0.f;
  #pragma unroll
  for (int i = 0; i < 3; ++i) {
    int c = tid + 256 * i;
    yv[i] = (xv[i] - mean) * rstd * g[c] + bb[c];
    ys += yv[i] * yv[i];
  }
  ys = blk_reduce_sum(ys, sm);
  float tc = sqrtf(expf(curv[0]) + ys);
  ushort_t* orow = lnp + (size_t)row * KPA;
  #pragma unroll
  for (int i = 0; i < 3; ++i) orow[1 + tid + 256 * i] = f2bf(yv[i]);
  if (tid == 0) orow[0] = f2bf(tc);
  if (tid < KPA - 769) orow[769 + tid] = 0;
}

// ------- fused: bf16 split-K reduce + bias + residual + final project -> out -
__global__ __launch_bounds__(256) void reduce_final_project(
    const ushort_t* __restrict__ Cp, int nsplit,
    const float* __restrict__ bias, const float* __restrict__ res,
    const float* __restrict__ curv, float* __restrict__ out) {
  __shared__ float sm[4];
  const int row = blockIdx.x;
  const int tid = threadIdx.x;
  float v[3]; float ss = 0.f;
  #pragma unroll
  for (int i = 0; i < 3; ++i) {
    const int c = tid + 256 * i;
    float t = bias[c] + res[(size_t)row * NE + c];
    for (int sp = 0; sp < nsplit; ++sp)
      t += bf2f(Cp[(size_t)sp * ROWS * NE + (size_t)row * NE + c]);
    v[i] = t; ss += t * t;
  }
  ss = blk_reduce_sum(ss, sm);
  float tc = sqrtf(expf(curv[0]) + ss);
  float* o = out + (size_t)row * 769;
  #pragma unroll
  for (int i = 0; i < 3; ++i) o[1 + tid + 256 * i] = v[i];
  if (tid == 0) o[0] = tc;
}

// ---------------- launcher ----------------
extern "C" void kernel_launch(void* const* d_in, const int* in_sizes, int n_in,
                              void* d_out, int out_size, void* d_ws, size_t ws_size,
                              hipStream_t stream) {
  (void)in_sizes; (void)n_in; (void)out_size; (void)ws_size;
  const float* x     = (const float*)d_in[0];
  const float* bc    = (const float*)d_in[1];
  const float* mc    = (const float*)d_in[2];
  const float* ac    = (const float*)d_in[3];
  const float* qkvw  = (const float*)d_in[4];
  const float* projw = (const float*)d_in[5];
  const float* projb = (const float*)d_in[6];
  const float* expw  = (const float*)d_in[7];
  const float* expb  = (const float*)d_in[8];
  const float* shrw  = (const float*)d_in[9];
  const float* shrb  = (const float*)d_in[10];
  const float* lng   = (const float*)d_in[11];
  const float* lnb   = (const float*)d_in[12];
  float* out = (float*)d_out;

  // ---- workspace layout (~120 MB worst phase) ----
  float* x2 = (float*)d_ws;                                  // 4096*768 f32
  ushort_t* qkv_wb  = (ushort_t*)(x2 + (size_t)ROWS * NE);   // 2304*832 bf16
  ushort_t* proj_wb = qkv_wb + (size_t)2304 * KPA;           // 768*832
  ushort_t* exp_wb  = proj_wb + (size_t)768 * KPA;           // 3200*832
  ushort_t* shr_wb  = exp_wb + (size_t)NEXP * KPA;           // 768*3136
  ushort_t* lnp_bf  = shr_wb + (size_t)768 * KPB;            // 4096*832
  ushort_t* aout_bf = lnp_bf + (size_t)ROWS * KPA;           // 4096*832
  char* r2 = (char*)(aout_bf + (size_t)ROWS * KPA);
  // r2 union #1 (attn phase)
  ushort_t* qkvb = (ushort_t*)r2;                            // ROWS*2304 bf16
  ushort_t* qbb = qkvb + (size_t)ROWS * 2304;
  ushort_t* kbb = qbb + (size_t)48 * T * 64;
  ushort_t* vtb = kbb + (size_t)48 * T * 64;
  float* q0b = (float*)(vtb + (size_t)48 * T * 64);
  float* k0b = q0b + (size_t)48 * T;
  float* v0b = k0b + (size_t)48 * T;
  ushort_t* Opart = (ushort_t*)(v0b + (size_t)48 * T);       // NSPLIT*48*T*64 bf16
  float* lpart = (float*)(Opart + (size_t)NSPLIT * 48 * T * 64);
  float* a0part = lpart + (size_t)NSPLIT * 48 * T;
  // proj split-K partials (alias r2 front — qkvb dead; Opart region starts
  // at +31.5MB, ppartP needs 12.6MB: no overlap)
  ushort_t* ppartP = (ushort_t*)r2;                          // 2*ROWS*768 bf16
  // r2 union #2 (mlp phase)
  ushort_t* hbbf = (ushort_t*)r2;                            // ROWS*NEXP bf16
  ushort_t* hp_bf = hbbf + (size_t)ROWS * NEXP;              // ROWS*KPB bf16
  ushort_t* ppartS = hp_bf + (size_t)ROWS * KPB;             // 4*ROWS*768 bf16

  // 0. merged weight conversions + pad zero + block_norm #1
  prep_kernel<<<NB_A + NB_B + NB_C + NB_D + NB_E + ROWS, 256, 0, stream>>>(
      qkv_wb, qkvw, proj_wb, projw, exp_wb, expw, shr_wb, shrw, aout_bf,
      x, lng, lnb, bc, lnp_bf);
  // 2. qkv = ln1p @ qkv_w^T  (bf16 out)
  gemm_bf16<<<dim3(2304 / 128, ROWS / 128, 1), 256, 0, stream>>>(
      lnp_bf, KPA, qkv_wb, KPA, qkvb, 2304, KPA / 64, KPA / 64,
      nullptr, 0, nullptr, 0, 1, nullptr);
  // 3. rotary + per-head project -> bf16 (V transposed)
  rope_project<<<(ROWS * NH) / 4, 256, 0, stream>>>(qkvb, ac, qbb, kbb, vtb, q0b, k0b, v0b);
  // 4. split-S MFMA Lorentz flash attention -> bf16 partials, then combine
  attn_kernel<<<dim3(NSPLIT, T / 64, 48), 256, 0, stream>>>(
      qbb, kbb, vtb, q0b, k0b, v0b, ac, Opart, lpart, a0part);
  attn_combine<<<(48 * T) / 4, 256, 0, stream>>>(Opart, lpart, a0part, ac, aout_bf);
  // 5+6. attn proj split-K=2 (bf16 partials), fused reduce+LN+project
  gemm_bf16<<<dim3(768 / 128, ROWS / 128, 2), 256, 0, stream>>>(
      aout_bf, KPA, proj_wb, KPA, nullptr, NE, KPA / 64, 7,
      nullptr, 0, nullptr, 0, 0, ppartP);
  reduce_ln_project<<<ROWS, 256, 0, stream>>>(
      ppartP, 2, projb, x, x2, lng, lnb, bc, lnp_bf);
  // 7. mlp expand + bias (bf16 out)
  gemm_bf16<<<dim3(NEXP / 128, ROWS / 128, 1), 256, 0, stream>>>(
      lnp_bf, KPA, exp_wb, KPA, hbbf, NEXP, KPA / 64, KPA / 64,
      expb, HEXP, nullptr, 0, 1, nullptr);
  // 8. gelu + project -> bf16
  gelu_project<<<ROWS, 256, 0, stream>>>(hbbf, mc, hp_bf);
  // 9+10. mlp shrink split-K=4 (bf16 partials), fused reduce+final project
  gemm_bf16<<<dim3(768 / 128, ROWS / 128, 4), 256, 0, stream>>>(
      hp_bf, KPB, shr_wb, KPB, nullptr, NE, KPB / 64, 13,
      nullptr, 0, nullptr, 0, 0, ppartS);
  reduce_final_project<<<ROWS, 256, 0, stream>>>(
      ppartS, 4, shrb, x2, bc, out);
}